// Round 12
// baseline (122.745 us; speedup 1.0000x reference)
//
#include <hip/hip_runtime.h>
#include <cstdint>
#include <math.h>

#define BATCH 32
#define NPIX (512*512)        // 262144 pixels per batch
#define NB1 1024              // level-1 bins: tp bits [31:22]
#define NCOPY 2               // LDS sub-histogram copies
#define NBA 2048              // select level A: tp bits [21:11]
#define NBB 2048              // select level B: tp bits [10:0]
#define PXB 2048              // pixels per block (256 thr * 8 px)
#define FGCAP 131072          // fg-list capacity per batch (16 MB total, 4B)
#define CAP 32768             // candidate capacity per batch (4 MB total)
#define CNTSTRIDE 32          // one cache line (128B) per batch counter

struct State {
    int      pfx1[BATCH];            // selected 10-bit prefix (-1 if no fg)
    uint32_t krem[BATCH];            // rank within pfx1 bin (1-based)
    uint32_t fgcnt  [BATCH*CNTSTRIDE];
    uint32_t candcnt[BATCH*CNTSTRIDE];
    double   I_low[BATCH];           // sum tp     over surely-kept fg
    double   U_low[BATCH];           // sum tp^2+1 over same
    double   S_bg [BATCH];           // sum p^2 over background
    double   I_cnd[BATCH];           // sum tp     over kept candidates
    double   U_cnd[BATCH];           // sum tp^2+1 over kept candidates
};

// ---------------------------------------------------------------------------
// k1: DMA-staged stream. global_load_lds moves each block's 32KB tile
// (4 streams x 8KB) to LDS with ZERO VGPR cost -> 8 loads in flight per wave,
// ~96KB/CU in flight across resident blocks (vs ~6 VGPR-bound loads before).
// Compute then runs out of LDS. Sigmoid softmax; LDS hist; block-aggregated
// fg append (1 returning atomic per block); wave-shuffle Sbg reduce.
// ---------------------------------------------------------------------------
__global__ __launch_bounds__(256)
void k_stream(const float* __restrict__ logits,
              const float* __restrict__ target,
              const float* __restrict__ eps,
              uint32_t* __restrict__ fgList,
              uint32_t* __restrict__ hist1,
              State* st)
{
    __shared__ __align__(16) float stage[4][PXB];   // 32 KB
    __shared__ uint32_t lh[NB1 * NCOPY];            // 8 KB
    __shared__ uint32_t wagg[4];
    __shared__ uint32_t blockbase;
    __shared__ double dsum[4];

    const int tid  = threadIdx.x;
    const int wid  = tid >> 6;
    const int lane = tid & 63;
    const int copy = tid & (NCOPY - 1);
    for (int i = tid; i < NB1 * NCOPY; i += 256) lh[i] = 0;

    const int b = blockIdx.y;
    const size_t nbase = (size_t)b * NPIX;
    const size_t lbase = (size_t)b * 2 * NPIX;
    const int base = blockIdx.x * PXB;

    // Issue all 8 DMA loads per wave (wave-uniform LDS base + lane*16).
#pragma unroll
    for (int it = 0; it < 2; ++it) {
        const int p0 = it * 1024 + wid * 256;   // float offset of wave chunk
        const int l4 = lane * 4;
        __builtin_amdgcn_global_load_lds(logits + lbase + base + p0 + l4,
                                         &stage[0][p0], 16, 0, 0);
        __builtin_amdgcn_global_load_lds(logits + lbase + NPIX + base + p0 + l4,
                                         &stage[1][p0], 16, 0, 0);
        __builtin_amdgcn_global_load_lds(target + nbase + base + p0 + l4,
                                         &stage[2][p0], 16, 0, 0);
        __builtin_amdgcn_global_load_lds(eps + nbase + base + p0 + l4,
                                         &stage[3][p0], 16, 0, 0);
    }
    __syncthreads();   // drains vmcnt (DMA) + lgkmcnt (lh init)

    uint32_t tpb_[8];
    uint32_t predmask = 0;
    double Sb0 = 0.0, Sb1 = 0.0;
#pragma unroll
    for (int it = 0; it < 2; ++it) {
        const int q = (it * 256 + tid) * 4;
        float4 l0 = *(const float4*)&stage[0][q];
        float4 l1 = *(const float4*)&stage[1][q];
        float4 tt = *(const float4*)&stage[2][q];
        float4 ee = *(const float4*)&stage[3][q];
        float a0[4] = {l0.x, l0.y, l0.z, l0.w};
        float a1[4] = {l1.x, l1.y, l1.z, l1.w};
        float tv[4] = {tt.x, tt.y, tt.z, tt.w};
        float ev[4] = {ee.x, ee.y, ee.z, ee.w};
#pragma unroll
        for (int j = 0; j < 4; ++j) {
            const int idx = it * 4 + j;
            float p  = 1.0f / (1.0f + expf(a0[j] - a1[j]));   // 2-ch softmax
            float tp = p * (tv[j] + ev[j]);
            bool fg  = (tv[j] == 1.0f);
            tpb_[idx] = __float_as_uint(tp);
            if (fg) {
                predmask |= (1u << idx);
                atomicAdd(&lh[(tpb_[idx] >> 22) * NCOPY + copy], 1u);
            } else {
                double pp = (double)p * (double)p;
                if (j & 1) Sb1 += pp; else Sb0 += pp;
            }
        }
    }

    // Block-aggregated fg append: wave prefix -> block prefix -> ONE atomic.
    uint32_t c = (uint32_t)__popc(predmask);
    uint32_t inc = c;
#pragma unroll
    for (int off = 1; off < 64; off <<= 1) {
        uint32_t v = __shfl_up(inc, off);
        if (lane >= off) inc += v;
    }
    uint32_t excl = inc - c;
    if (lane == 63) wagg[wid] = inc;
    __syncthreads();
    if (tid == 0) {
        uint32_t tot = wagg[0] + wagg[1] + wagg[2] + wagg[3];
        blockbase = tot ? atomicAdd(&st->fgcnt[b * CNTSTRIDE], tot) : 0u;
    }
    __syncthreads();
    uint32_t wbase = blockbase;
    for (int w = 0; w < wid; ++w) wbase += wagg[w];

    uint32_t* fgb = fgList + (size_t)b * FGCAP;
    uint32_t pos = wbase + excl;
#pragma unroll
    for (int idx = 0; idx < 8; ++idx) {
        if ((predmask >> idx) & 1u) {
            if (pos < FGCAP) fgb[pos] = tpb_[idx];
            pos++;
        }
    }

    // Hist flush.
    uint32_t* hb = hist1 + (size_t)b * NB1;
    for (int bin = tid; bin < NB1; bin += 256) {
        uint32_t v = lh[bin * NCOPY + 0] + lh[bin * NCOPY + 1];
        if (v) atomicAdd(hb + bin, v);
    }

    // Sbg: wave shuffle reduce, one atomic per block.
    double s = Sb0 + Sb1;
#pragma unroll
    for (int off = 32; off > 0; off >>= 1) s += __shfl_down(s, off);
    if (lane == 0) dsum[wid] = s;
    __syncthreads();
    if (tid == 0) atomicAdd(&st->S_bg[b], dsum[0] + dsum[1] + dsum[2] + dsum[3]);
}

// ---------------------------------------------------------------------------
// Scan level-1: pick 10-bit prefix containing rank k = max(1, n_fg/2).
// ---------------------------------------------------------------------------
__global__ __launch_bounds__(256)
void k_scan1(const uint32_t* __restrict__ hist1, State* st)
{
    const int b = blockIdx.x;
    const int t = threadIdx.x;
    const uint32_t* h = hist1 + (size_t)b * NB1;
    __shared__ uint32_t part[256];
    __shared__ int sBin; __shared__ uint32_t sRem;
    if (t == 0) { sBin = 0; sRem = 1; }

    const int g = NB1 / 256;   // 4
    uint32_t s = 0;
    for (int j = 0; j < g; ++j) s += h[t * g + j];
    part[t] = s;
    __syncthreads();
    for (int off = 1; off < 256; off <<= 1) {
        uint32_t v = (t >= off) ? part[t - off] : 0u;
        __syncthreads();
        part[t] += v;
        __syncthreads();
    }
    uint32_t incl = part[t], excl = incl - s;
    uint32_t total = part[255];
    if (total == 0) {
        if (t == 0) { st->pfx1[b] = -1; st->krem[b] = 0; }
        return;
    }
    uint32_t k = total / 2;
    if (k == 0) k = 1;

    if (excl < k && k <= incl) {
        uint32_t run = excl;
        for (int j = 0; j < g; ++j) {
            uint32_t c = h[t * g + j];
            if (run < k && k <= run + c) { sBin = t * g + j; sRem = k - run; break; }
            run += c;
        }
    }
    __syncthreads();
    if (t == 0) { st->pfx1[b] = sBin; st->krem[b] = sRem; }
}

// ---------------------------------------------------------------------------
// k_sums: pass over fg-list. bin<pfx1 -> I/U_low; bin==pfx1 -> LDS histA +
// wave-aggregated candidate append.
// ---------------------------------------------------------------------------
__global__ __launch_bounds__(256)
void k_sums(const uint32_t* __restrict__ fgList,
            State* st, uint32_t* __restrict__ cand,
            uint32_t* __restrict__ histA)
{
    __shared__ uint32_t lhA[NBA];          // 8 KB
    const int tid = threadIdx.x;
    const int lane = tid & 63;
    const unsigned long long lmask = (1ULL << lane) - 1ULL;
    for (int i = tid; i < NBA; i += 256) lhA[i] = 0;
    __syncthreads();

    const int b = blockIdx.y;
    const int pfx = st->pfx1[b];
    if (pfx < 0) return;
    const uint32_t n = min(st->fgcnt[b * CNTSTRIDE], (uint32_t)FGCAP);
    const uint32_t* fgb = fgList + (size_t)b * FGCAP;
    uint32_t* cb = cand + (size_t)b * CAP;

    double Il = 0.0, Ul = 0.0;
    for (uint32_t i = blockIdx.x * 256 + tid; i < n; i += gridDim.x * 256) {
        uint32_t bits = fgb[i];
        int bin = (int)(bits >> 22);
        bool isc = (bin == pfx);
        if (bin < pfx) {
            float tp = __uint_as_float(bits);
            Il += (double)tp;
            Ul += (double)tp * (double)tp + 1.0;
        } else if (isc) {
            atomicAdd(&lhA[(bits >> 11) & (NBA - 1)], 1u);
        }
        unsigned long long msk = __ballot(isc);
        if (msk) {
            int leader = __ffsll((long long)msk) - 1;
            uint32_t cnt = (uint32_t)__popcll(msk);
            uint32_t basec = 0;
            if (lane == leader) basec = atomicAdd(&st->candcnt[b * CNTSTRIDE], cnt);
            basec = __shfl(basec, leader);
            if (isc) {
                uint32_t off = (uint32_t)__popcll(msk & lmask);
                uint32_t pos = basec + off;
                if (pos < CAP) cb[pos] = bits;
            }
        }
    }

    __syncthreads();
    uint32_t* hA = histA + (size_t)b * NBA;
    for (int i = tid; i < NBA; i += 256) {
        uint32_t v = lhA[i];
        if (v) atomicAdd(hA + i, v);
    }

    __shared__ double sI[256];
    __shared__ double sU[256];
    sI[tid] = Il; sU[tid] = Ul;
    __syncthreads();
    for (int off = 128; off > 0; off >>= 1) {
        if (tid < off) { sI[tid] += sI[tid+off]; sU[tid] += sU[tid+off]; }
        __syncthreads();
    }
    if (tid == 0) {
        atomicAdd(&st->I_low[b], sI[0]);
        atomicAdd(&st->U_low[b], sU[0]);
    }
}

// ---------------------------------------------------------------------------
#define SELECT_BIN(h, nb, k)                                                  \
    {                                                                         \
        const int g = (nb) / 256;                                             \
        uint32_t s = 0;                                                       \
        for (int j = 0; j < g; ++j) s += (h)[t * g + j];                      \
        part[t] = s;                                                          \
        __syncthreads();                                                      \
        for (int off = 1; off < 256; off <<= 1) {                             \
            uint32_t v = (t >= off) ? part[t - off] : 0u;                     \
            __syncthreads();                                                  \
            part[t] += v;                                                     \
            __syncthreads();                                                  \
        }                                                                     \
        uint32_t incl = part[t], excl = incl - s;                             \
        if (excl < (k) && (k) <= incl) {                                      \
            uint32_t run = excl;                                              \
            for (int j = 0; j < g; ++j) {                                     \
                uint32_t c = (h)[t * g + j];                                  \
                if (run < (k) && (k) <= run + c) {                            \
                    sBin = t * g + j;                                         \
                    sRem = (k) - run;                                         \
                    break;                                                    \
                }                                                             \
                run += c;                                                     \
            }                                                                 \
        }                                                                     \
        __syncthreads();                                                      \
    }

// ---------------------------------------------------------------------------
// Fused select: scan histA -> binA; histB over binA candidates -> binB -> thr;
// final pass over candidate list: bits <= thr -> kept sums. One block/batch.
// ---------------------------------------------------------------------------
__global__ __launch_bounds__(256)
void k_selectAB(State* st, const uint32_t* __restrict__ cand,
                const uint32_t* __restrict__ histA)
{
    const int b = blockIdx.x;
    const int t = threadIdx.x;
    const int pfx = st->pfx1[b];
    if (pfx < 0) return;
    const uint32_t kA = st->krem[b];
    const uint32_t n = min(st->candcnt[b * CNTSTRIDE], (uint32_t)CAP);
    const uint32_t* cb = cand + (size_t)b * CAP;
    const uint32_t* hA = histA + (size_t)b * NBA;

    __shared__ uint32_t part[256];
    __shared__ int sBin; __shared__ uint32_t sRem;
    __shared__ uint32_t lhB[NBB];          // 8 KB

    if (t == 0) { sBin = 0; sRem = 1; }
    __syncthreads();
    SELECT_BIN(hA, NBA, kA);
    const uint32_t binA = (uint32_t)sBin;
    const uint32_t kB = sRem;
    __syncthreads();
    if (t == 0) { sBin = 0; sRem = 1; }

    for (int i = t; i < NBB; i += 256) lhB[i] = 0;
    __syncthreads();
    for (uint32_t i = t; i < n; i += 256) {
        uint32_t bits = cb[i];
        if (((bits >> 11) & (NBA - 1)) == binA)
            atomicAdd(&lhB[bits & (NBB - 1)], 1u);
    }
    __syncthreads();
    SELECT_BIN(lhB, NBB, kB);
    const uint32_t binB = (uint32_t)sBin;
    const uint32_t thr_bits = ((uint32_t)pfx << 22) | (binA << 11) | binB;

    double I = 0.0, U = 0.0;
    for (uint32_t i = t; i < n; i += 256) {
        uint32_t bits = cb[i];
        if (bits <= thr_bits) {
            float tp = __uint_as_float(bits);
            I += (double)tp;
            U += (double)tp * (double)tp + 1.0;
        }
    }
    __shared__ double sI[256];
    __shared__ double sU[256];
    sI[t] = I; sU[t] = U;
    __syncthreads();
    for (int off = 128; off > 0; off >>= 1) {
        if (t < off) { sI[t] += sI[t+off]; sU[t] += sU[t+off]; }
        __syncthreads();
    }
    if (t == 0) {
        st->I_cnd[b] = sI[0];     // single block per batch: plain store
        st->U_cnd[b] = sU[0];
    }
}

__global__ void k_finalize(const State* __restrict__ st, float* __restrict__ out)
{
    const int t = threadIdx.x;
    double d = 0.0;
    if (t < BATCH) {
        double I = st->I_low[t] + st->I_cnd[t];
        double U = st->U_low[t] + st->U_cnd[t] + st->S_bg[t];
        d = (2.0 * I + 1e-5) / (U + 1e-5);
    }
    for (int off = 32; off > 0; off >>= 1) d += __shfl_down(d, off);
    if (t == 0) out[0] = (float)(1.0 - d / (double)BATCH);
}

// ---------------------------------------------------------------------------
extern "C" void kernel_launch(void* const* d_in, const int* in_sizes, int n_in,
                              void* d_out, int out_size, void* d_ws, size_t ws_size,
                              hipStream_t stream) {
    const float* logits = (const float*)d_in[0];
    const float* target = (const float*)d_in[1];
    const float* eps    = (const float*)d_in[2];
    float* out = (float*)d_out;

    char* ws = (char*)d_ws;
    const size_t h1B = (size_t)BATCH * NB1 * 4;            // 128 KB
    const size_t hAB = (size_t)BATCH * NBA * 4;            // 256 KB
    uint32_t* hist1 = (uint32_t*)ws;
    uint32_t* histA = (uint32_t*)(ws + h1B);
    State* st = (State*)(ws + h1B + hAB);
    const size_t baseNeed = h1B + hAB + sizeof(State);

    size_t off = ((baseNeed + 255) / 256) * 256;
    uint32_t* fgList = (uint32_t*)(ws + off);              // 16 MB
    off += (size_t)BATCH * FGCAP * sizeof(uint32_t);
    uint32_t* cand = (uint32_t*)(ws + off);                // 4 MB
    off += (size_t)BATCH * CAP * sizeof(uint32_t);

    // Zero histograms + state each call (graph-capture safe).
    hipMemsetAsync(ws, 0, baseNeed, stream);

    dim3 grid(NPIX / PXB, BATCH);   // 128 x 32 = 4096 blocks
    k_stream  <<<grid, 256, 0, stream>>>(logits, target, eps, fgList, hist1, st);
    k_scan1   <<<BATCH, 256, 0, stream>>>(hist1, st);
    k_sums    <<<dim3(16, BATCH), 256, 0, stream>>>(fgList, st, cand, histA);
    k_selectAB<<<BATCH, 256, 0, stream>>>(st, cand, histA);
    k_finalize<<<1, 64, 0, stream>>>(st, out);
}

// Round 14
// 108.428 us; speedup vs baseline: 1.1320x; 1.1320x over previous
//
#include <hip/hip_runtime.h>
#include <cstdint>
#include <math.h>

#define BATCH 32
#define NPIX (512*512)        // 262144 pixels per batch
#define NB1 1024              // level-1 bins: tp bits [31:22]
#define NCOPY 4               // LDS sub-histogram copies
#define NBA 2048              // select level A: tp bits [21:11]
#define NBB 2048              // select level B: tp bits [10:0]
#define PXB 4096              // pixels per block (256 thr * 16 px)
#define CAP 32768             // candidate capacity per batch (4 MB total)
#define CNTSTRIDE 32          // one cache line (128B) per batch counter

typedef float vfloat4 __attribute__((ext_vector_type(4)));

struct State {
    int      pfx1[BATCH];            // selected 10-bit prefix (-1 if no fg)
    uint32_t krem[BATCH];            // rank within pfx1 bin (1-based)
    uint32_t candcnt[BATCH*CNTSTRIDE];
    double   I_low[BATCH];           // sum tp     over surely-kept fg
    double   U_low[BATCH];           // sum tp^2+1 over same
    double   S_bg [BATCH];           // sum p^2 over background
    double   I_cnd[BATCH];           // sum tp     over kept candidates
    double   U_cnd[BATCH];           // sum tp^2+1 over kept candidates
};

// ---------------------------------------------------------------------------
// Pass 1 (hot): read 128 MB, sigmoid softmax, nt-store tpv (fg->tp, bg->-p),
// LDS count histogram. NO append machinery (measured fastest form: R6/R8/R9).
// ---------------------------------------------------------------------------
__global__ __launch_bounds__(256)
void k_pass1(const float* __restrict__ logits,
             const float* __restrict__ target,
             const float* __restrict__ eps,
             float* __restrict__ tpv,
             uint32_t* __restrict__ hist1)
{
    __shared__ uint32_t lh[NB1 * NCOPY];   // 16 KB
    const int tid = threadIdx.x;
    const int copy = tid & (NCOPY - 1);
    for (int i = tid; i < NB1 * NCOPY; i += 256) lh[i] = 0;
    __syncthreads();

    const int b = blockIdx.y;
    const size_t nbase = (size_t)b * NPIX;
    const size_t lbase = (size_t)b * 2 * NPIX;
    const int base = blockIdx.x * PXB;

    float4 L0[4], L1[4], T4[4], E4[4];
#pragma unroll
    for (int it = 0; it < 4; ++it) {
        const int i0 = base + (it * 256 + tid) * 4;
        L0[it] = *(const float4*)(logits + lbase + i0);
        L1[it] = *(const float4*)(logits + lbase + NPIX + i0);
        T4[it] = *(const float4*)(target + nbase + i0);
        E4[it] = *(const float4*)(eps    + nbase + i0);
    }

#pragma unroll
    for (int it = 0; it < 4; ++it) {
        const int i0 = base + (it * 256 + tid) * 4;
        float a0[4] = {L0[it].x, L0[it].y, L0[it].z, L0[it].w};
        float a1[4] = {L1[it].x, L1[it].y, L1[it].z, L1[it].w};
        float tv[4] = {T4[it].x, T4[it].y, T4[it].z, T4[it].w};
        float ev[4] = {E4[it].x, E4[it].y, E4[it].z, E4[it].w};
        vfloat4 vv;
#pragma unroll
        for (int j = 0; j < 4; ++j) {
            // 2-channel softmax == sigmoid of logit difference (verified R11).
            float p  = 1.0f / (1.0f + expf(a0[j] - a1[j]));
            float tp = p * (tv[j] + ev[j]);
            bool fg  = (tv[j] == 1.0f);
            if (fg) {
                atomicAdd(&lh[(__float_as_uint(tp) >> 22) * NCOPY + copy], 1u);
                vv[j] = tp;              // positive
            } else {
                vv[j] = -p;              // sign bit marks background
            }
        }
        __builtin_nontemporal_store(vv, (vfloat4*)(tpv + nbase + i0));
    }

    __syncthreads();
    uint32_t* hb = hist1 + (size_t)b * NB1;
    for (int bin = tid; bin < NB1; bin += 256) {
        uint32_t v = lh[bin*NCOPY+0] + lh[bin*NCOPY+1] + lh[bin*NCOPY+2] + lh[bin*NCOPY+3];
        if (v) atomicAdd(hb + bin, v);
    }
}

// ---------------------------------------------------------------------------
// Scan level-1: pick 10-bit prefix containing rank k = max(1, n_fg/2).
// ---------------------------------------------------------------------------
__global__ __launch_bounds__(256)
void k_scan1(const uint32_t* __restrict__ hist1, State* st)
{
    const int b = blockIdx.x;
    const int t = threadIdx.x;
    const uint32_t* h = hist1 + (size_t)b * NB1;
    __shared__ uint32_t part[256];
    __shared__ int sBin; __shared__ uint32_t sRem;
    if (t == 0) { sBin = 0; sRem = 1; }

    const int g = NB1 / 256;   // 4
    uint32_t s = 0;
    for (int j = 0; j < g; ++j) s += h[t * g + j];
    part[t] = s;
    __syncthreads();
    for (int off = 1; off < 256; off <<= 1) {
        uint32_t v = (t >= off) ? part[t - off] : 0u;
        __syncthreads();
        part[t] += v;
        __syncthreads();
    }
    uint32_t incl = part[t], excl = incl - s;
    uint32_t total = part[255];
    if (total == 0) {
        if (t == 0) { st->pfx1[b] = -1; st->krem[b] = 0; }
        return;
    }
    uint32_t k = total / 2;
    if (k == 0) k = 1;

    if (excl < k && k <= incl) {
        uint32_t run = excl;
        for (int j = 0; j < g; ++j) {
            uint32_t c = h[t * g + j];
            if (run < k && k <= run + c) { sBin = t * g + j; sRem = k - run; break; }
            run += c;
        }
    }
    __syncthreads();
    if (t == 0) { st->pfx1[b] = sBin; st->krem[b] = sRem; }
}

// ---------------------------------------------------------------------------
// Pass 2: read tpv (32 MB, L3-warm). bg -> S_bg; fg bin<pfx1 -> I/U_low;
// bin==pfx1 -> LDS histA + wave-aggregated candidate append (deferred masks).
// NOTE: no early-return on pfx1<0 — S_bg must still accumulate.
// ---------------------------------------------------------------------------
__global__ __launch_bounds__(256)
void k_pass2(const float* __restrict__ tpv,
             State* st, uint32_t* __restrict__ cand,
             uint32_t* __restrict__ histA)
{
    const int b = blockIdx.y;
    const int tid = threadIdx.x;
    const int lane = tid & 63;
    const int pfx = st->pfx1[b];
    const size_t nbase = (size_t)b * NPIX;
    const int base = blockIdx.x * PXB;
    uint32_t* cb = cand + (size_t)b * CAP;

    __shared__ uint32_t lhA[NBA];          // 8 KB
    for (int i = tid; i < NBA; i += 256) lhA[i] = 0;
    __syncthreads();

    float4 V4[4];
#pragma unroll
    for (int it = 0; it < 4; ++it) {
        const int i0 = base + (it * 256 + tid) * 4;
        V4[it] = *(const float4*)(tpv + nbase + i0);
    }

    uint32_t tpb_[16];
    uint32_t predmask = 0;
    double Il = 0.0, Ul = 0.0, Sbg = 0.0;
#pragma unroll
    for (int it = 0; it < 4; ++it) {
        float vv[4] = {V4[it].x, V4[it].y, V4[it].z, V4[it].w};
#pragma unroll
        for (int j = 0; j < 4; ++j) {
            const int idx = it * 4 + j;
            uint32_t bits = __float_as_uint(vv[j]);
            tpb_[idx] = bits;
            if (bits >> 31) {                       // background: -p
                float p = __uint_as_float(bits & 0x7FFFFFFFu);
                Sbg += (double)p * (double)p;
            } else {                                // foreground: tp
                int bin = (int)(bits >> 22);
                float tp = vv[j];
                if (bin < pfx) {
                    Il += (double)tp;
                    Ul += (double)tp * (double)tp + 1.0;
                } else if (bin == pfx) {
                    predmask |= (1u << idx);
                    atomicAdd(&lhA[(bits >> 11) & (NBA - 1)], 1u);
                }
            }
        }
    }

    // Wave-aggregated append: ONE returning atomic per wave.
    uint32_t c = (uint32_t)__popc(predmask);
    uint32_t inc = c;
#pragma unroll
    for (int off = 1; off < 64; off <<= 1) {
        uint32_t v = __shfl_up(inc, off);
        if (lane >= off) inc += v;
    }
    uint32_t excl = inc - c;
    uint32_t wtotal = __shfl(inc, 63);
    uint32_t basec = 0;
    if (lane == 0 && wtotal) basec = atomicAdd(&st->candcnt[b * CNTSTRIDE], wtotal);
    basec = __shfl(basec, 0);

    uint32_t pos = basec + excl;
#pragma unroll
    for (int idx = 0; idx < 16; ++idx) {
        if ((predmask >> idx) & 1u) {
            if (pos < CAP) cb[pos] = tpb_[idx];
            pos++;
        }
    }

    __syncthreads();
    uint32_t* hA = histA + (size_t)b * NBA;
    for (int i = tid; i < NBA; i += 256) {
        uint32_t v = lhA[i];
        if (v) atomicAdd(hA + i, v);
    }

    __shared__ double sI[256];
    __shared__ double sU[256];
    __shared__ double sB[256];
    sI[tid] = Il; sU[tid] = Ul; sB[tid] = Sbg;
    __syncthreads();
    for (int off = 128; off > 0; off >>= 1) {
        if (tid < off) { sI[tid] += sI[tid+off]; sU[tid] += sU[tid+off]; sB[tid] += sB[tid+off]; }
        __syncthreads();
    }
    if (tid == 0) {
        atomicAdd(&st->I_low[b], sI[0]);
        atomicAdd(&st->U_low[b], sU[0]);
        atomicAdd(&st->S_bg[b],  sB[0]);
    }
}

// ---------------------------------------------------------------------------
#define SELECT_BIN(h, nb, k)                                                  \
    {                                                                         \
        const int g = (nb) / 256;                                             \
        uint32_t s = 0;                                                       \
        for (int j = 0; j < g; ++j) s += (h)[t * g + j];                      \
        part[t] = s;                                                          \
        __syncthreads();                                                      \
        for (int off = 1; off < 256; off <<= 1) {                             \
            uint32_t v = (t >= off) ? part[t - off] : 0u;                     \
            __syncthreads();                                                  \
            part[t] += v;                                                     \
            __syncthreads();                                                  \
        }                                                                     \
        uint32_t incl = part[t], excl = incl - s;                             \
        if (excl < (k) && (k) <= incl) {                                      \
            uint32_t run = excl;                                              \
            for (int j = 0; j < g; ++j) {                                     \
                uint32_t c = (h)[t * g + j];                                  \
                if (run < (k) && (k) <= run + c) {                            \
                    sBin = t * g + j;                                         \
                    sRem = (k) - run;                                         \
                    break;                                                    \
                }                                                             \
                run += c;                                                     \
            }                                                                 \
        }                                                                     \
        __syncthreads();                                                      \
    }

// ---------------------------------------------------------------------------
// Fused select (verified R12): scan histA -> binA; LDS histB over binA
// candidates -> binB -> thr; pass over candidates: bits <= thr -> kept sums.
// One block per batch.
// ---------------------------------------------------------------------------
__global__ __launch_bounds__(256)
void k_selectAB(State* st, const uint32_t* __restrict__ cand,
                const uint32_t* __restrict__ histA)
{
    const int b = blockIdx.x;
    const int t = threadIdx.x;
    const int pfx = st->pfx1[b];
    if (pfx < 0) return;                   // I_cnd/U_cnd stay 0 (memset)
    const uint32_t kA = st->krem[b];
    const uint32_t n = min(st->candcnt[b * CNTSTRIDE], (uint32_t)CAP);
    const uint32_t* cb = cand + (size_t)b * CAP;
    const uint32_t* hA = histA + (size_t)b * NBA;

    __shared__ uint32_t part[256];
    __shared__ int sBin; __shared__ uint32_t sRem;
    __shared__ uint32_t lhB[NBB];          // 8 KB

    if (t == 0) { sBin = 0; sRem = 1; }
    __syncthreads();
    SELECT_BIN(hA, NBA, kA);
    const uint32_t binA = (uint32_t)sBin;
    const uint32_t kB = sRem;
    __syncthreads();
    if (t == 0) { sBin = 0; sRem = 1; }

    for (int i = t; i < NBB; i += 256) lhB[i] = 0;
    __syncthreads();
    for (uint32_t i = t; i < n; i += 256) {
        uint32_t bits = cb[i];
        if (((bits >> 11) & (NBA - 1)) == binA)
            atomicAdd(&lhB[bits & (NBB - 1)], 1u);
    }
    __syncthreads();
    SELECT_BIN(lhB, NBB, kB);
    const uint32_t binB = (uint32_t)sBin;
    const uint32_t thr_bits = ((uint32_t)pfx << 22) | (binA << 11) | binB;

    double I = 0.0, U = 0.0;
    for (uint32_t i = t; i < n; i += 256) {
        uint32_t bits = cb[i];
        if (bits <= thr_bits) {
            float tp = __uint_as_float(bits);
            I += (double)tp;
            U += (double)tp * (double)tp + 1.0;
        }
    }
    __shared__ double sI[256];
    __shared__ double sU[256];
    sI[t] = I; sU[t] = U;
    __syncthreads();
    for (int off = 128; off > 0; off >>= 1) {
        if (t < off) { sI[t] += sI[t+off]; sU[t] += sU[t+off]; }
        __syncthreads();
    }
    if (t == 0) {
        st->I_cnd[b] = sI[0];              // single block per batch
        st->U_cnd[b] = sU[0];
    }
}

__global__ void k_finalize(const State* __restrict__ st, float* __restrict__ out)
{
    const int t = threadIdx.x;
    double d = 0.0;
    if (t < BATCH) {
        double I = st->I_low[t] + st->I_cnd[t];
        double U = st->U_low[t] + st->U_cnd[t] + st->S_bg[t];
        d = (2.0 * I + 1e-5) / (U + 1e-5);
    }
    for (int off = 32; off > 0; off >>= 1) d += __shfl_down(d, off);
    if (t == 0) out[0] = (float)(1.0 - d / (double)BATCH);
}

// ---------------------------------------------------------------------------
extern "C" void kernel_launch(void* const* d_in, const int* in_sizes, int n_in,
                              void* d_out, int out_size, void* d_ws, size_t ws_size,
                              hipStream_t stream) {
    const float* logits = (const float*)d_in[0];
    const float* target = (const float*)d_in[1];
    const float* eps    = (const float*)d_in[2];
    float* out = (float*)d_out;

    char* ws = (char*)d_ws;
    const size_t h1B = (size_t)BATCH * NB1 * 4;            // 128 KB
    const size_t hAB = (size_t)BATCH * NBA * 4;            // 256 KB
    uint32_t* hist1 = (uint32_t*)ws;
    uint32_t* histA = (uint32_t*)(ws + h1B);
    State* st = (State*)(ws + h1B + hAB);
    const size_t baseNeed = h1B + hAB + sizeof(State);

    size_t off = ((baseNeed + 255) / 256) * 256;
    uint32_t* cand = (uint32_t*)(ws + off);                // 4 MB
    off += (size_t)BATCH * CAP * sizeof(uint32_t);
    float* tpv = (float*)(ws + off);                       // 32 MB
    off += (size_t)BATCH * NPIX * sizeof(float);

    // Zero histograms + state each call (graph-capture safe).
    hipMemsetAsync(ws, 0, baseNeed, stream);

    dim3 grid(NPIX / PXB, BATCH);   // 64 x 32 = 2048 blocks
    k_pass1   <<<grid, 256, 0, stream>>>(logits, target, eps, tpv, hist1);
    k_scan1   <<<BATCH, 256, 0, stream>>>(hist1, st);
    k_pass2   <<<grid, 256, 0, stream>>>(tpv, st, cand, histA);
    k_selectAB<<<BATCH, 256, 0, stream>>>(st, cand, histA);
    k_finalize<<<1, 64, 0, stream>>>(st, out);
}

// Round 15
// 95.461 us; speedup vs baseline: 1.2858x; 1.1358x over previous
//
#include <hip/hip_runtime.h>
#include <cstdint>
#include <math.h>

#define BATCH 32
#define NPIX (512*512)        // 262144 pixels per batch
#define NB1 1024              // level-1 bins: tp bits [31:22]
#define NCC 2                 // LDS sub-copies for count hist
#define NCS 2                 // LDS sub-copies for sum hists
#define NBA 2048              // select level A: tp bits [21:11]
#define NBB 2048              // select level B: tp bits [10:0]
#define PXB 4096              // pixels per block (256 thr * 16 px)
#define CAP 32768             // candidate capacity per batch (4 MB total)
#define CAP2 8192             // binA-candidate capacity per batch (1 MB total)
#define CNTSTRIDE 32          // one cache line (128B) per batch counter

typedef float vfloat4 __attribute__((ext_vector_type(4)));

struct State {
    int      pfx1[BATCH];            // selected 10-bit prefix (-1 if no fg)
    uint32_t krem[BATCH];            // rank within pfx1 bin (1-based)
    int      binA[BATCH];            // selected level-A bin
    uint32_t remA[BATCH];            // rank within binA (1-based)
    uint32_t candcnt[BATCH*CNTSTRIDE];
    uint32_t cnt2   [BATCH*CNTSTRIDE];
    double   I_low[BATCH];           // sum tp     over bins < pfx1
    double   U_low[BATCH];           // sum tp^2+1 over same
    double   S_bg [BATCH];           // sum p^2 over background
    double   I_cnd[BATCH];           // sum tp     over kept candidates
    double   U_cnd[BATCH];           // sum tp^2+1 over kept candidates
};

// ---------------------------------------------------------------------------
// Pass 1 (hot): read 128 MB, sigmoid softmax, nt-store tpv (fg->tp, bg->-p).
// Per-bin LDS: count + sum(tp) + sum(tp^2)  ->  I_low/U_low need NO data pass.
// S_bg in f64 registers. (R14's fastest structure + aggregates.)
// ---------------------------------------------------------------------------
__global__ __launch_bounds__(256)
void k_pass1(const float* __restrict__ logits,
             const float* __restrict__ target,
             const float* __restrict__ eps,
             float* __restrict__ tpv,
             uint32_t* __restrict__ hist1,
             double* __restrict__ sumT,
             double* __restrict__ sumQ,
             State* st)
{
    __shared__ uint32_t lc[NB1 * NCC];     // 8 KB counts
    __shared__ float    ls[NB1 * NCS];     // 8 KB sum tp
    __shared__ float    lq[NB1 * NCS];     // 8 KB sum tp^2
    const int tid = threadIdx.x;
    const int cc = tid & (NCC - 1);
    const int cs = tid & (NCS - 1);
    for (int i = tid; i < NB1 * NCC; i += 256) lc[i] = 0;
    for (int i = tid; i < NB1 * NCS; i += 256) { ls[i] = 0.0f; lq[i] = 0.0f; }
    __syncthreads();

    const int b = blockIdx.y;
    const size_t nbase = (size_t)b * NPIX;
    const size_t lbase = (size_t)b * 2 * NPIX;
    const int base = blockIdx.x * PXB;

    float4 L0[4], L1[4], T4[4], E4[4];
#pragma unroll
    for (int it = 0; it < 4; ++it) {
        const int i0 = base + (it * 256 + tid) * 4;
        L0[it] = *(const float4*)(logits + lbase + i0);
        L1[it] = *(const float4*)(logits + lbase + NPIX + i0);
        T4[it] = *(const float4*)(target + nbase + i0);
        E4[it] = *(const float4*)(eps    + nbase + i0);
    }

    double Sb0 = 0.0, Sb1 = 0.0;
#pragma unroll
    for (int it = 0; it < 4; ++it) {
        const int i0 = base + (it * 256 + tid) * 4;
        float a0[4] = {L0[it].x, L0[it].y, L0[it].z, L0[it].w};
        float a1[4] = {L1[it].x, L1[it].y, L1[it].z, L1[it].w};
        float tv[4] = {T4[it].x, T4[it].y, T4[it].z, T4[it].w};
        float ev[4] = {E4[it].x, E4[it].y, E4[it].z, E4[it].w};
        vfloat4 vv;
#pragma unroll
        for (int j = 0; j < 4; ++j) {
            // 2-channel softmax == sigmoid of logit difference (verified R11).
            float p  = 1.0f / (1.0f + expf(a0[j] - a1[j]));
            float tp = p * (tv[j] + ev[j]);
            bool fg  = (tv[j] == 1.0f);
            if (fg) {
                uint32_t bin = __float_as_uint(tp) >> 22;
                atomicAdd(&lc[bin * NCC + cc], 1u);
                atomicAdd(&ls[bin * NCS + cs], tp);
                atomicAdd(&lq[bin * NCS + cs], tp * tp);
                vv[j] = tp;              // positive
            } else {
                double pp = (double)p * (double)p;
                if (j & 1) Sb1 += pp; else Sb0 += pp;
                vv[j] = -p;              // sign bit marks background
            }
        }
        __builtin_nontemporal_store(vv, (vfloat4*)(tpv + nbase + i0));
    }

    __syncthreads();
    uint32_t* hb = hist1 + (size_t)b * NB1;
    double* sT = sumT + (size_t)b * NB1;
    double* sQ = sumQ + (size_t)b * NB1;
    for (int bin = tid; bin < NB1; bin += 256) {
        uint32_t v = lc[bin*NCC+0] + lc[bin*NCC+1];
        if (v) {
            atomicAdd(hb + bin, v);
            atomicAdd(sT + bin, (double)(ls[bin*NCS+0] + ls[bin*NCS+1]));
            atomicAdd(sQ + bin, (double)(lq[bin*NCS+0] + lq[bin*NCS+1]));
        }
    }

    __shared__ double sB[256];
    sB[tid] = Sb0 + Sb1;
    __syncthreads();
    for (int off = 128; off > 0; off >>= 1) {
        if (tid < off) sB[tid] += sB[tid + off];
        __syncthreads();
    }
    if (tid == 0) atomicAdd(&st->S_bg[b], sB[0]);
}

// ---------------------------------------------------------------------------
// Scan level-1: pick bin containing rank k = max(1, n_fg/2); then I_low/U_low
// directly from the per-bin aggregates (bins < pfx1).
// ---------------------------------------------------------------------------
__global__ __launch_bounds__(256)
void k_scan1(const uint32_t* __restrict__ hist1,
             const double* __restrict__ sumT,
             const double* __restrict__ sumQ,
             State* st)
{
    const int b = blockIdx.x;
    const int t = threadIdx.x;
    const uint32_t* h = hist1 + (size_t)b * NB1;
    const double* sT = sumT + (size_t)b * NB1;
    const double* sQ = sumQ + (size_t)b * NB1;
    __shared__ uint32_t part[256];
    __shared__ int sBin; __shared__ uint32_t sRem;
    __shared__ double dI[256];
    __shared__ double dU[256];
    if (t == 0) { sBin = 0; sRem = 1; }

    const int g = NB1 / 256;   // 4
    uint32_t s = 0;
    for (int j = 0; j < g; ++j) s += h[t * g + j];
    part[t] = s;
    __syncthreads();
    for (int off = 1; off < 256; off <<= 1) {
        uint32_t v = (t >= off) ? part[t - off] : 0u;
        __syncthreads();
        part[t] += v;
        __syncthreads();
    }
    uint32_t incl = part[t], excl = incl - s;
    uint32_t total = part[255];
    if (total == 0) {
        if (t == 0) { st->pfx1[b] = -1; st->krem[b] = 0; }
        return;
    }
    uint32_t k = total / 2;
    if (k == 0) k = 1;

    if (excl < k && k <= incl) {
        uint32_t run = excl;
        for (int j = 0; j < g; ++j) {
            uint32_t c = h[t * g + j];
            if (run < k && k <= run + c) { sBin = t * g + j; sRem = k - run; break; }
            run += c;
        }
    }
    __syncthreads();
    const int pfx = sBin;

    // I_low / U_low from aggregates over bins < pfx.
    double It = 0.0, Ut = 0.0;
    uint32_t cl = 0;
    for (int j = 0; j < g; ++j) {
        const int idx = t * g + j;
        if (idx < pfx) { It += sT[idx]; Ut += sQ[idx]; cl += h[idx]; }
    }
    dI[t] = It; dU[t] = Ut; part[t] = cl;
    __syncthreads();
    for (int off = 128; off > 0; off >>= 1) {
        if (t < off) { dI[t] += dI[t+off]; dU[t] += dU[t+off]; part[t] += part[t+off]; }
        __syncthreads();
    }
    if (t == 0) {
        st->pfx1[b] = pfx;
        st->krem[b] = sRem;
        st->I_low[b] = dI[0];
        st->U_low[b] = dU[0] + (double)part[0];   // +1 per kept fg element
    }
}

// ---------------------------------------------------------------------------
// Pass 2 (lean): pure filter of tpv (32 MB, L3-warm). Only bin==pfx1 matters:
// LDS histA + wave-aggregated candidate append. No sums, no bg work.
// ---------------------------------------------------------------------------
__global__ __launch_bounds__(256)
void k_pass2(const float* __restrict__ tpv,
             State* st, uint32_t* __restrict__ cand,
             uint32_t* __restrict__ histA)
{
    const int b = blockIdx.y;
    const int tid = threadIdx.x;
    const int lane = tid & 63;
    const int pfx = st->pfx1[b];     // -1 never matches a real bin
    const size_t nbase = (size_t)b * NPIX;
    const int base = blockIdx.x * PXB;
    uint32_t* cb = cand + (size_t)b * CAP;

    __shared__ uint32_t lhA[NBA];          // 8 KB
    for (int i = tid; i < NBA; i += 256) lhA[i] = 0;
    __syncthreads();

    float4 V4[4];
#pragma unroll
    for (int it = 0; it < 4; ++it) {
        const int i0 = base + (it * 256 + tid) * 4;
        V4[it] = *(const float4*)(tpv + nbase + i0);
    }

    uint32_t tpb_[16];
    uint32_t predmask = 0;
#pragma unroll
    for (int it = 0; it < 4; ++it) {
        float vv[4] = {V4[it].x, V4[it].y, V4[it].z, V4[it].w};
#pragma unroll
        for (int j = 0; j < 4; ++j) {
            const int idx = it * 4 + j;
            uint32_t bits = __float_as_uint(vv[j]);
            tpb_[idx] = bits;
            // bg has sign bit -> bits>>22 >= 512+... never equals pfx (<1024
            // and bg top bit makes value >= 0x200); fg: compare bin.
            if (!(bits >> 31) && (int)(bits >> 22) == pfx) {
                predmask |= (1u << idx);
                atomicAdd(&lhA[(bits >> 11) & (NBA - 1)], 1u);
            }
        }
    }

    // Wave-aggregated append: ONE returning atomic per wave.
    uint32_t c = (uint32_t)__popc(predmask);
    uint32_t inc = c;
#pragma unroll
    for (int off = 1; off < 64; off <<= 1) {
        uint32_t v = __shfl_up(inc, off);
        if (lane >= off) inc += v;
    }
    uint32_t excl = inc - c;
    uint32_t wtotal = __shfl(inc, 63);
    uint32_t basec = 0;
    if (lane == 0 && wtotal) basec = atomicAdd(&st->candcnt[b * CNTSTRIDE], wtotal);
    basec = __shfl(basec, 0);

    uint32_t pos = basec + excl;
#pragma unroll
    for (int idx = 0; idx < 16; ++idx) {
        if ((predmask >> idx) & 1u) {
            if (pos < CAP) cb[pos] = tpb_[idx];
            pos++;
        }
    }

    __syncthreads();
    uint32_t* hA = histA + (size_t)b * NBA;
    for (int i = tid; i < NBA; i += 256) {
        uint32_t v = lhA[i];
        if (v) atomicAdd(hA + i, v);
    }
}

// ---------------------------------------------------------------------------
#define SELECT_BIN(h, nb, k)                                                  \
    {                                                                         \
        const int g = (nb) / 256;                                             \
        uint32_t s = 0;                                                       \
        for (int j = 0; j < g; ++j) s += (h)[t * g + j];                      \
        part[t] = s;                                                          \
        __syncthreads();                                                      \
        for (int off = 1; off < 256; off <<= 1) {                             \
            uint32_t v = (t >= off) ? part[t - off] : 0u;                     \
            __syncthreads();                                                  \
            part[t] += v;                                                     \
            __syncthreads();                                                  \
        }                                                                     \
        uint32_t incl = part[t], excl = incl - s;                             \
        if (excl < (k) && (k) <= incl) {                                      \
            uint32_t run = excl;                                              \
            for (int j = 0; j < g; ++j) {                                     \
                uint32_t c = (h)[t * g + j];                                  \
                if (run < (k) && (k) <= run + c) {                            \
                    sBin = t * g + j;                                         \
                    sRem = (k) - run;                                         \
                    break;                                                    \
                }                                                             \
                run += c;                                                     \
            }                                                                 \
        }                                                                     \
        __syncthreads();                                                      \
    }

__global__ __launch_bounds__(256)
void k_scanA(const uint32_t* __restrict__ histA, State* st)
{
    const int b = blockIdx.x;
    const int t = threadIdx.x;
    if (st->pfx1[b] < 0) return;
    const uint32_t* h = histA + (size_t)b * NBA;
    const uint32_t k = st->krem[b];
    __shared__ uint32_t part[256];
    __shared__ int sBin; __shared__ uint32_t sRem;
    if (t == 0) { sBin = 0; sRem = 1; }
    __syncthreads();
    SELECT_BIN(h, NBA, k);
    if (t == 0) { st->binA[b] = sBin; st->remA[b] = sRem; }
}

// ---------------------------------------------------------------------------
// Level-B pass over candidates (parallel, 4 blocks/batch): sub<binA -> kept
// sums; sub==binA -> LDS histB + compact into tiny cand2 list.
// ---------------------------------------------------------------------------
__global__ __launch_bounds__(256)
void k_histB(State* st, const uint32_t* __restrict__ cand,
             uint32_t* __restrict__ histB, uint32_t* __restrict__ cand2)
{
    const int b = blockIdx.y;
    const int t = threadIdx.x;
    if (st->pfx1[b] < 0) return;
    const uint32_t binA = (uint32_t)st->binA[b];
    const uint32_t n = min(st->candcnt[b * CNTSTRIDE], (uint32_t)CAP);
    const uint32_t* cb = cand + (size_t)b * CAP;
    uint32_t* c2 = cand2 + (size_t)b * CAP2;

    __shared__ uint32_t lhB[NBB];          // 8 KB
    for (int i = t; i < NBB; i += 256) lhB[i] = 0;
    __syncthreads();

    double I = 0.0, U = 0.0;
    for (uint32_t i = blockIdx.x * 256 + t; i < n; i += gridDim.x * 256) {
        uint32_t bits = cb[i];
        uint32_t sub = (bits >> 11) & (NBA - 1);
        if (sub < binA) {
            float tp = __uint_as_float(bits);
            I += (double)tp;
            U += (double)tp * (double)tp + 1.0;
        } else if (sub == binA) {
            atomicAdd(&lhB[bits & (NBB - 1)], 1u);
            uint32_t pos = atomicAdd(&st->cnt2[b * CNTSTRIDE], 1u);
            if (pos < CAP2) c2[pos] = bits;
        }
    }

    __syncthreads();
    uint32_t* hB = histB + (size_t)b * NBB;
    for (int i = t; i < NBB; i += 256) {
        uint32_t v = lhB[i];
        if (v) atomicAdd(hB + i, v);
    }

    __shared__ double sI[256];
    __shared__ double sU[256];
    sI[t] = I; sU[t] = U;
    __syncthreads();
    for (int off = 128; off > 0; off >>= 1) {
        if (t < off) { sI[t] += sI[t+off]; sU[t] += sU[t+off]; }
        __syncthreads();
    }
    if (t == 0) {
        atomicAdd(&st->I_cnd[b], sI[0]);
        atomicAdd(&st->U_cnd[b], sU[0]);
    }
}

// ---------------------------------------------------------------------------
__global__ __launch_bounds__(256)
void k_scanB(State* st, const uint32_t* __restrict__ histB,
             const uint32_t* __restrict__ cand2)
{
    const int b = blockIdx.x;
    const int t = threadIdx.x;
    const int pfx = st->pfx1[b];
    if (pfx < 0) return;
    const uint32_t* h = histB + (size_t)b * NBB;
    const uint32_t k = st->remA[b];
    const uint32_t binA = (uint32_t)st->binA[b];
    const uint32_t* c2 = cand2 + (size_t)b * CAP2;
    const uint32_t n2 = min(st->cnt2[b * CNTSTRIDE], (uint32_t)CAP2);

    __shared__ uint32_t part[256];
    __shared__ int sBin; __shared__ uint32_t sRem;
    if (t == 0) { sBin = 0; sRem = 1; }
    __syncthreads();
    SELECT_BIN(h, NBB, k);
    const uint32_t binB = (uint32_t)sBin;
    const uint32_t thr_bits = ((uint32_t)pfx << 22) | (binA << 11) | binB;

    double I = 0.0, U = 0.0;
    for (uint32_t i = t; i < n2; i += 256) {
        uint32_t bits = c2[i];
        if (bits <= thr_bits) {
            float tp = __uint_as_float(bits);
            I += (double)tp;
            U += (double)tp * (double)tp + 1.0;
        }
    }
    __shared__ double sI[256];
    __shared__ double sU[256];
    sI[t] = I; sU[t] = U;
    __syncthreads();
    for (int off = 128; off > 0; off >>= 1) {
        if (t < off) { sI[t] += sI[t+off]; sU[t] += sU[t+off]; }
        __syncthreads();
    }
    if (t == 0) {
        atomicAdd(&st->I_cnd[b], sI[0]);
        atomicAdd(&st->U_cnd[b], sU[0]);
    }
}

__global__ void k_finalize(const State* __restrict__ st, float* __restrict__ out)
{
    const int t = threadIdx.x;
    double d = 0.0;
    if (t < BATCH) {
        double I = st->I_low[t] + st->I_cnd[t];
        double U = st->U_low[t] + st->U_cnd[t] + st->S_bg[t];
        d = (2.0 * I + 1e-5) / (U + 1e-5);
    }
    for (int off = 32; off > 0; off >>= 1) d += __shfl_down(d, off);
    if (t == 0) out[0] = (float)(1.0 - d / (double)BATCH);
}

// ---------------------------------------------------------------------------
extern "C" void kernel_launch(void* const* d_in, const int* in_sizes, int n_in,
                              void* d_out, int out_size, void* d_ws, size_t ws_size,
                              hipStream_t stream) {
    const float* logits = (const float*)d_in[0];
    const float* target = (const float*)d_in[1];
    const float* eps    = (const float*)d_in[2];
    float* out = (float*)d_out;

    char* ws = (char*)d_ws;
    size_t off = 0;
    uint32_t* hist1 = (uint32_t*)(ws + off); off += (size_t)BATCH * NB1 * 4;   // 128 KB
    uint32_t* histA = (uint32_t*)(ws + off); off += (size_t)BATCH * NBA * 4;   // 256 KB
    uint32_t* histB = (uint32_t*)(ws + off); off += (size_t)BATCH * NBB * 4;   // 256 KB
    double*   sumT  = (double*)  (ws + off); off += (size_t)BATCH * NB1 * 8;   // 256 KB
    double*   sumQ  = (double*)  (ws + off); off += (size_t)BATCH * NB1 * 8;   // 256 KB
    State*    st    = (State*)   (ws + off); off += sizeof(State);
    const size_t baseNeed = off;

    off = ((off + 255) / 256) * 256;
    uint32_t* cand  = (uint32_t*)(ws + off); off += (size_t)BATCH * CAP  * 4;  // 4 MB
    uint32_t* cand2 = (uint32_t*)(ws + off); off += (size_t)BATCH * CAP2 * 4;  // 1 MB
    float*    tpv   = (float*)   (ws + off); off += (size_t)BATCH * NPIX * 4;  // 32 MB

    // Zero histograms + aggregates + state each call (graph-capture safe).
    hipMemsetAsync(ws, 0, baseNeed, stream);

    dim3 grid(NPIX / PXB, BATCH);   // 64 x 32 = 2048 blocks
    k_pass1 <<<grid, 256, 0, stream>>>(logits, target, eps, tpv, hist1, sumT, sumQ, st);
    k_scan1 <<<BATCH, 256, 0, stream>>>(hist1, sumT, sumQ, st);
    k_pass2 <<<grid, 256, 0, stream>>>(tpv, st, cand, histA);
    k_scanA <<<BATCH, 256, 0, stream>>>(histA, st);
    k_histB <<<dim3(4, BATCH), 256, 0, stream>>>(st, cand, histB, cand2);
    k_scanB <<<BATCH, 256, 0, stream>>>(st, histB, cand2);
    k_finalize<<<1, 64, 0, stream>>>(st, out);
}

// Round 16
// 75.835 us; speedup vs baseline: 1.6186x; 1.2588x over previous
//
#include <hip/hip_runtime.h>
#include <cstdint>
#include <math.h>

#define BATCH 32
#define NPIX (512*512)        // 262144 pixels per batch
#define NB1 4096              // level-1 bins: tp bits [30:19] (tp>0 -> bit31=0)
#define NBA 2048              // select level A: tp bits [18:8]
#define NBB 256               // select level B: tp bits [7:0]
#define PXB 4096              // pixels per block (256 thr * 16 px)
#define CAP 32768             // candidate capacity per batch (4 MB total)
#define LCAP 8192             // LDS-resident candidate cap in selectAB (32 KB)
#define CNTSTRIDE 32          // one cache line (128B) per batch counter

typedef float vfloat4 __attribute__((ext_vector_type(4)));

struct State {
    int      pfx1[BATCH];            // selected 12-bit prefix (-1 if no fg)
    uint32_t krem[BATCH];            // rank within pfx1 bin (1-based)
    uint32_t candcnt[BATCH*CNTSTRIDE];
    double   I_low[BATCH];           // sum tp     over bins < pfx1
    double   U_low[BATCH];           // sum tp^2+1 over same
    double   S_bg [BATCH];           // sum p^2 over background
    double   I_cnd[BATCH];           // sum tp     over kept candidates
    double   U_cnd[BATCH];           // sum tp^2+1 over kept candidates
};

// ---------------------------------------------------------------------------
// Pass 1 (hot, R14 structure EXACTLY: 16KB LDS, one count atomic per fg px,
// sigmoid softmax, nt-store). Only change: 4096 bins (bits[30:19]), NCOPY=1
// -- same LDS footprint and slot count as R14's 1024x4.
// Sbg accumulated here in f64 registers (2 chains).
// ---------------------------------------------------------------------------
__global__ __launch_bounds__(256)
void k_pass1(const float* __restrict__ logits,
             const float* __restrict__ target,
             const float* __restrict__ eps,
             float* __restrict__ tpv,
             uint32_t* __restrict__ hist1,
             State* st)
{
    __shared__ uint32_t lh[NB1];           // 16 KB
    const int tid = threadIdx.x;
    for (int i = tid; i < NB1; i += 256) lh[i] = 0;
    __syncthreads();

    const int b = blockIdx.y;
    const size_t nbase = (size_t)b * NPIX;
    const size_t lbase = (size_t)b * 2 * NPIX;
    const int base = blockIdx.x * PXB;

    float4 L0[4], L1[4], T4[4], E4[4];
#pragma unroll
    for (int it = 0; it < 4; ++it) {
        const int i0 = base + (it * 256 + tid) * 4;
        L0[it] = *(const float4*)(logits + lbase + i0);
        L1[it] = *(const float4*)(logits + lbase + NPIX + i0);
        T4[it] = *(const float4*)(target + nbase + i0);
        E4[it] = *(const float4*)(eps    + nbase + i0);
    }

    double Sb0 = 0.0, Sb1 = 0.0;
#pragma unroll
    for (int it = 0; it < 4; ++it) {
        const int i0 = base + (it * 256 + tid) * 4;
        float a0[4] = {L0[it].x, L0[it].y, L0[it].z, L0[it].w};
        float a1[4] = {L1[it].x, L1[it].y, L1[it].z, L1[it].w};
        float tv[4] = {T4[it].x, T4[it].y, T4[it].z, T4[it].w};
        float ev[4] = {E4[it].x, E4[it].y, E4[it].z, E4[it].w};
        vfloat4 vv;
#pragma unroll
        for (int j = 0; j < 4; ++j) {
            // 2-channel softmax == sigmoid of logit difference (verified R11).
            float p  = 1.0f / (1.0f + expf(a0[j] - a1[j]));
            float tp = p * (tv[j] + ev[j]);
            bool fg  = (tv[j] == 1.0f);
            if (fg) {
                atomicAdd(&lh[__float_as_uint(tp) >> 19], 1u);  // tp>0: 12 bits
                vv[j] = tp;              // positive
            } else {
                double pp = (double)p * (double)p;
                if (j & 1) Sb1 += pp; else Sb0 += pp;
                vv[j] = -p;              // sign bit marks background
            }
        }
        __builtin_nontemporal_store(vv, (vfloat4*)(tpv + nbase + i0));
    }

    __syncthreads();
    uint32_t* hb = hist1 + (size_t)b * NB1;
    for (int bin = tid; bin < NB1; bin += 256) {
        uint32_t v = lh[bin];
        if (v) atomicAdd(hb + bin, v);
    }

    __shared__ double sB[256];
    sB[tid] = Sb0 + Sb1;
    __syncthreads();
    for (int off = 128; off > 0; off >>= 1) {
        if (tid < off) sB[tid] += sB[tid + off];
        __syncthreads();
    }
    if (tid == 0) atomicAdd(&st->S_bg[b], sB[0]);
}

// ---------------------------------------------------------------------------
// Scan level-1 (4096 bins): pick bin containing rank k = max(1, n_fg/2).
// ---------------------------------------------------------------------------
__global__ __launch_bounds__(256)
void k_scan1(const uint32_t* __restrict__ hist1, State* st)
{
    const int b = blockIdx.x;
    const int t = threadIdx.x;
    const uint32_t* h = hist1 + (size_t)b * NB1;
    __shared__ uint32_t part[256];
    __shared__ int sBin; __shared__ uint32_t sRem;
    if (t == 0) { sBin = 0; sRem = 1; }

    const int g = NB1 / 256;   // 16
    uint32_t s = 0;
    for (int j = 0; j < g; ++j) s += h[t * g + j];
    part[t] = s;
    __syncthreads();
    for (int off = 1; off < 256; off <<= 1) {
        uint32_t v = (t >= off) ? part[t - off] : 0u;
        __syncthreads();
        part[t] += v;
        __syncthreads();
    }
    uint32_t incl = part[t], excl = incl - s;
    uint32_t total = part[255];
    if (total == 0) {
        if (t == 0) { st->pfx1[b] = -1; st->krem[b] = 0; }
        return;
    }
    uint32_t k = total / 2;
    if (k == 0) k = 1;

    if (excl < k && k <= incl) {
        uint32_t run = excl;
        for (int j = 0; j < g; ++j) {
            uint32_t c = h[t * g + j];
            if (run < k && k <= run + c) { sBin = t * g + j; sRem = k - run; break; }
            run += c;
        }
    }
    __syncthreads();
    if (t == 0) { st->pfx1[b] = sBin; st->krem[b] = sRem; }
}

// ---------------------------------------------------------------------------
// Pass 2 (dense, R9-measured form minus histA): read tpv (32 MB, L3-warm).
// fg bin<pfx1 -> I/U_low f64 register sums; bin==pfx1 -> wave-agg append.
// ---------------------------------------------------------------------------
__global__ __launch_bounds__(256)
void k_pass2(const float* __restrict__ tpv,
             State* st, uint32_t* __restrict__ cand)
{
    const int b = blockIdx.y;
    const int tid = threadIdx.x;
    const int lane = tid & 63;
    const int pfx = st->pfx1[b];     // -1: no bin matches (bin >= 0)
    const size_t nbase = (size_t)b * NPIX;
    const int base = blockIdx.x * PXB;
    uint32_t* cb = cand + (size_t)b * CAP;

    float4 V4[4];
#pragma unroll
    for (int it = 0; it < 4; ++it) {
        const int i0 = base + (it * 256 + tid) * 4;
        V4[it] = *(const float4*)(tpv + nbase + i0);
    }

    uint32_t tpb_[16];
    uint32_t predmask = 0;
    double Il = 0.0, Ul = 0.0;
#pragma unroll
    for (int it = 0; it < 4; ++it) {
        float vv[4] = {V4[it].x, V4[it].y, V4[it].z, V4[it].w};
#pragma unroll
        for (int j = 0; j < 4; ++j) {
            const int idx = it * 4 + j;
            uint32_t bits = __float_as_uint(vv[j]);
            tpb_[idx] = bits;
            if (!(bits >> 31)) {                    // foreground: tp
                int bin = (int)(bits >> 19);
                if (bin < pfx) {
                    float tp = vv[j];
                    Il += (double)tp;
                    Ul += (double)tp * (double)tp + 1.0;
                } else if (bin == pfx) {
                    predmask |= (1u << idx);
                }
            }
        }
    }

    // Wave-aggregated append: ONE returning atomic per wave.
    uint32_t c = (uint32_t)__popc(predmask);
    uint32_t inc = c;
#pragma unroll
    for (int off = 1; off < 64; off <<= 1) {
        uint32_t v = __shfl_up(inc, off);
        if (lane >= off) inc += v;
    }
    uint32_t excl = inc - c;
    uint32_t wtotal = __shfl(inc, 63);
    uint32_t basec = 0;
    if (lane == 0 && wtotal) basec = atomicAdd(&st->candcnt[b * CNTSTRIDE], wtotal);
    basec = __shfl(basec, 0);

    uint32_t pos = basec + excl;
#pragma unroll
    for (int idx = 0; idx < 16; ++idx) {
        if ((predmask >> idx) & 1u) {
            if (pos < CAP) cb[pos] = tpb_[idx];
            pos++;
        }
    }

    __shared__ double sI[256];
    __shared__ double sU[256];
    sI[tid] = Il; sU[tid] = Ul;
    __syncthreads();
    for (int off = 128; off > 0; off >>= 1) {
        if (tid < off) { sI[tid] += sI[tid+off]; sU[tid] += sU[tid+off]; }
        __syncthreads();
    }
    if (tid == 0) {
        atomicAdd(&st->I_low[b], sI[0]);
        atomicAdd(&st->U_low[b], sU[0]);
    }
}

// ---------------------------------------------------------------------------
#define SELECT_BIN_L(ld, nb, k)                                               \
    {                                                                         \
        const int g = (nb) / 256;                                             \
        uint32_t s = 0;                                                       \
        for (int j = 0; j < g; ++j) s += (ld)[t * g + j];                     \
        part[t] = s;                                                          \
        __syncthreads();                                                      \
        for (int off = 1; off < 256; off <<= 1) {                             \
            uint32_t v = (t >= off) ? part[t - off] : 0u;                     \
            __syncthreads();                                                  \
            part[t] += v;                                                     \
            __syncthreads();                                                  \
        }                                                                     \
        uint32_t incl = part[t], excl = incl - s;                             \
        if (excl < (k) && (k) <= incl) {                                      \
            uint32_t run = excl;                                              \
            for (int j = 0; j < g; ++j) {                                     \
                uint32_t c = (ld)[t * g + j];                                 \
                if (run < (k) && (k) <= run + c) {                            \
                    sBin = t * g + j;                                         \
                    sRem = (k) - run;                                         \
                    break;                                                    \
                }                                                             \
                run += c;                                                     \
            }                                                                 \
        }                                                                     \
        __syncthreads();                                                      \
    }

// ---------------------------------------------------------------------------
// Fused select, LDS-resident: copy candidate list (n ~ 1-3K with 4096 bins)
// into LDS once; level A (bits[18:8], 2048 bins) -> binA; level B (bits[7:0],
// 256 bins) -> binB -> thr; kept sums. All loops hit LDS, not global.
// One block per batch. Falls back to global reads if n > LCAP.
// ---------------------------------------------------------------------------
__global__ __launch_bounds__(256)
void k_selectAB(State* st, const uint32_t* __restrict__ cand)
{
    const int b = blockIdx.x;
    const int t = threadIdx.x;
    const int pfx = st->pfx1[b];
    if (pfx < 0) return;                   // I_cnd/U_cnd stay 0 (memset)
    const uint32_t kA = st->krem[b];
    const uint32_t n = min(st->candcnt[b * CNTSTRIDE], (uint32_t)CAP);
    const uint32_t* cb = cand + (size_t)b * CAP;

    __shared__ uint32_t cstore[LCAP];      // 32 KB
    __shared__ uint32_t lh[NBA];           // 8 KB (reused for level B)
    __shared__ uint32_t part[256];
    __shared__ int sBin; __shared__ uint32_t sRem;

    const bool inLDS = (n <= (uint32_t)LCAP);
    if (inLDS) {
        for (uint32_t i = t; i < n; i += 256) cstore[i] = cb[i];
    }

    // Level A histogram: bits [18:8].
    for (int i = t; i < NBA; i += 256) lh[i] = 0;
    if (t == 0) { sBin = 0; sRem = 1; }
    __syncthreads();
    for (uint32_t i = t; i < n; i += 256) {
        uint32_t bits = inLDS ? cstore[i] : cb[i];
        atomicAdd(&lh[(bits >> 8) & (NBA - 1)], 1u);
    }
    __syncthreads();
    SELECT_BIN_L(lh, NBA, kA);
    const uint32_t binA = (uint32_t)sBin;
    const uint32_t kB = sRem;
    __syncthreads();

    // Level B histogram: bits [7:0] within binA.
    for (int i = t; i < NBB; i += 256) lh[i] = 0;
    if (t == 0) { sBin = 0; sRem = 1; }
    __syncthreads();
    for (uint32_t i = t; i < n; i += 256) {
        uint32_t bits = inLDS ? cstore[i] : cb[i];
        if (((bits >> 8) & (NBA - 1)) == binA)
            atomicAdd(&lh[bits & (NBB - 1)], 1u);
    }
    __syncthreads();
    SELECT_BIN_L(lh, NBB, kB);
    const uint32_t binB = (uint32_t)sBin;
    const uint32_t thr_bits = ((uint32_t)pfx << 19) | (binA << 8) | binB;

    // Kept-candidate sums (ties kept: bits <= thr).
    double I = 0.0, U = 0.0;
    for (uint32_t i = t; i < n; i += 256) {
        uint32_t bits = inLDS ? cstore[i] : cb[i];
        if (bits <= thr_bits) {
            float tp = __uint_as_float(bits);
            I += (double)tp;
            U += (double)tp * (double)tp + 1.0;
        }
    }
    __shared__ double sI[256];
    __shared__ double sU[256];
    sI[t] = I; sU[t] = U;
    __syncthreads();
    for (int off = 128; off > 0; off >>= 1) {
        if (t < off) { sI[t] += sI[t+off]; sU[t] += sU[t+off]; }
        __syncthreads();
    }
    if (t == 0) {
        st->I_cnd[b] = sI[0];              // single block per batch
        st->U_cnd[b] = sU[0];
    }
}

__global__ void k_finalize(const State* __restrict__ st, float* __restrict__ out)
{
    const int t = threadIdx.x;
    double d = 0.0;
    if (t < BATCH) {
        double I = st->I_low[t] + st->I_cnd[t];
        double U = st->U_low[t] + st->U_cnd[t] + st->S_bg[t];
        d = (2.0 * I + 1e-5) / (U + 1e-5);
    }
    for (int off = 32; off > 0; off >>= 1) d += __shfl_down(d, off);
    if (t == 0) out[0] = (float)(1.0 - d / (double)BATCH);
}

// ---------------------------------------------------------------------------
extern "C" void kernel_launch(void* const* d_in, const int* in_sizes, int n_in,
                              void* d_out, int out_size, void* d_ws, size_t ws_size,
                              hipStream_t stream) {
    const float* logits = (const float*)d_in[0];
    const float* target = (const float*)d_in[1];
    const float* eps    = (const float*)d_in[2];
    float* out = (float*)d_out;

    char* ws = (char*)d_ws;
    size_t off = 0;
    uint32_t* hist1 = (uint32_t*)(ws + off); off += (size_t)BATCH * NB1 * 4;   // 512 KB
    State*    st    = (State*)   (ws + off); off += sizeof(State);
    const size_t baseNeed = off;

    off = ((off + 255) / 256) * 256;
    uint32_t* cand = (uint32_t*)(ws + off); off += (size_t)BATCH * CAP * 4;    // 4 MB
    float*    tpv  = (float*)   (ws + off); off += (size_t)BATCH * NPIX * 4;   // 32 MB

    // Zero histogram + state each call (graph-capture safe).
    hipMemsetAsync(ws, 0, baseNeed, stream);

    dim3 grid(NPIX / PXB, BATCH);   // 64 x 32 = 2048 blocks
    k_pass1   <<<grid, 256, 0, stream>>>(logits, target, eps, tpv, hist1, st);
    k_scan1   <<<BATCH, 256, 0, stream>>>(hist1, st);
    k_pass2   <<<grid, 256, 0, stream>>>(tpv, st, cand);
    k_selectAB<<<BATCH, 256, 0, stream>>>(st, cand);
    k_finalize<<<1, 64, 0, stream>>>(st, out);
}